// Round 2
// baseline (81.070 us; speedup 1.0000x reference)
//
#include <hip/hip_runtime.h>

#define NB 4
#define CB 8
#define DB 196
#define MBd 128
#define KBc 64
#define ROWS (NB*CB*DB)      // 6272
#define ROWLEN (KBc*MBd)     // 8192
#define CNTF ((float)(NB*DB*KBc*MBd))  // 6422528

// ---------------- Kernel 1: per-row BN partial sums ----------------
__global__ __launch_bounds__(256) void k_stats(const float* __restrict__ x,
                                               const float* __restrict__ cent,
                                               float* __restrict__ partial)
{
    __shared__ float cs[KBc*MBd];   // 32 KB centroids
    __shared__ float xs[MBd];
    __shared__ float red[8];
    const int t = threadIdx.x;
    const int r = blockIdx.x;

    // stage centroids (8192 f32) -> LDS
    const float4* c4 = (const float4*)cent;
    float4* cs4 = (float4*)cs;
#pragma unroll
    for (int i = 0; i < 8; ++i) cs4[i*256 + t] = c4[i*256 + t];
    // stage this row of x (128 f32)
    if (t < 64) {
        float2 v = ((const float2*)(x + (size_t)r*MBd))[t];
        xs[2*t]   = v.x;
        xs[2*t+1] = v.y;
    }
    __syncthreads();

    const int l  = t & 63;
    const int w  = t >> 6;
    const int g  = l >> 4;
    const int li = l & 15;
    const int mb = li*8;

    // x-row L2 norm (redundant per wave, deterministic)
    float s = xs[l]*xs[l] + xs[l+64]*xs[l+64];
#pragma unroll
    for (int o = 32; o >= 1; o >>= 1) s += __shfl_xor(s, o, 64);
    const float xr = 1.0f / fmaxf(sqrtf(s), 1e-12f);

    float xm[8];
#pragma unroll
    for (int j = 0; j < 8; ++j) xm[j] = xs[mb+j]*xr;

    float s1 = 0.f, s2 = 0.f;
#pragma unroll
    for (int it = 0; it < 4; ++it) {
        const int k = it*16 + w*4 + g;
        const float* cr = &cs[k*MBd + mb];
        float u[8]; float ss = 0.f;
#pragma unroll
        for (int j = 0; j < 8; ++j) { u[j] = xm[j] - cr[j]; ss = fmaf(u[j], u[j], ss); }
#pragma unroll
        for (int o = 8; o >= 1; o >>= 1) ss += __shfl_xor(ss, o, 64);
        const float rn = 1.0f / fmaxf(sqrtf(ss), 1e-12f);
#pragma unroll
        for (int j = 0; j < 8; ++j) { float v = u[j]*rn; s1 += v; s2 = fmaf(v, v, s2); }
    }
    // block reduce (fixed order -> deterministic)
#pragma unroll
    for (int o = 32; o >= 1; o >>= 1) { s1 += __shfl_xor(s1, o, 64); s2 += __shfl_xor(s2, o, 64); }
    if (l == 0) { red[w] = s1; red[4+w] = s2; }
    __syncthreads();
    if (t == 0) {
        partial[2*r]   = red[0]+red[1]+red[2]+red[3];
        partial[2*r+1] = red[4]+red[5]+red[6]+red[7];
    }
}

// ---------------- Kernel 2: per-channel mean / inv_std ----------------
__global__ __launch_bounds__(256) void k_reduce(const float* __restrict__ partial,
                                                float* __restrict__ stats)
{
    __shared__ float rs1[256], rs2[256];
    const int c = blockIdx.x, t = threadIdx.x;
    float s1 = 0.f, s2 = 0.f;
    for (int idx = t; idx < NB*DB; idx += 256) {
        int n = idx / DB, d = idx % DB;
        int r = (n*CB + c)*DB + d;
        s1 += partial[2*r]; s2 += partial[2*r+1];
    }
    rs1[t] = s1; rs2[t] = s2; __syncthreads();
#pragma unroll
    for (int sdiv = 128; sdiv >= 1; sdiv >>= 1) {
        if (t < sdiv) { rs1[t] += rs1[t+sdiv]; rs2[t] += rs2[t+sdiv]; }
        __syncthreads();
    }
    if (t == 0) {
        float mean = rs1[0] / CNTF;
        float var  = rs2[0] / CNTF - mean*mean;
        stats[2*c]   = mean;
        stats[2*c+1] = 1.0f / sqrtf(var + 1e-5f);
    }
}

// ---------------- Kernel 3: recompute, BN affine, final l2norm, write ----------------
__global__ __launch_bounds__(256) void k_out(const float* __restrict__ x,
                                             const float* __restrict__ cent,
                                             const float* __restrict__ stats,
                                             const float* __restrict__ gamma,
                                             const float* __restrict__ beta,
                                             float* __restrict__ out)
{
    __shared__ float cs[KBc*MBd];
    __shared__ float xs[MBd];
    __shared__ float red[8];
    const int t = threadIdx.x;
    const int r = blockIdx.x;

    const float4* c4 = (const float4*)cent;
    float4* cs4 = (float4*)cs;
#pragma unroll
    for (int i = 0; i < 8; ++i) cs4[i*256 + t] = c4[i*256 + t];
    if (t < 64) {
        float2 v = ((const float2*)(x + (size_t)r*MBd))[t];
        xs[2*t]   = v.x;
        xs[2*t+1] = v.y;
    }
    __syncthreads();

    const int l  = t & 63;
    const int w  = t >> 6;
    const int g  = l >> 4;
    const int li = l & 15;
    const int mb = li*8;

    const int c = (r / DB) % CB;
    const float mean = stats[2*c];
    const float istd = stats[2*c+1];
    const float aa = istd * gamma[c];
    const float bb = beta[c] - mean * aa;

    float s = xs[l]*xs[l] + xs[l+64]*xs[l+64];
#pragma unroll
    for (int o = 32; o >= 1; o >>= 1) s += __shfl_xor(s, o, 64);
    const float xr = 1.0f / fmaxf(sqrtf(s), 1e-12f);

    float xm[8];
#pragma unroll
    for (int j = 0; j < 8; ++j) xm[j] = xs[mb+j]*xr;

    float y[4][8];
    float yss = 0.f;
#pragma unroll
    for (int it = 0; it < 4; ++it) {
        const int k = it*16 + w*4 + g;
        const float* cr = &cs[k*MBd + mb];
        float u[8]; float ss = 0.f;
#pragma unroll
        for (int j = 0; j < 8; ++j) { u[j] = xm[j] - cr[j]; ss = fmaf(u[j], u[j], ss); }
#pragma unroll
        for (int o = 8; o >= 1; o >>= 1) ss += __shfl_xor(ss, o, 64);
        const float rn = 1.0f / fmaxf(sqrtf(ss), 1e-12f);
#pragma unroll
        for (int j = 0; j < 8; ++j) {
            float v = u[j]*rn;
            float yy = fmaf(v, aa, bb);
            y[it][j] = yy;
            yss = fmaf(yy, yy, yss);
        }
    }
    // block-reduce row sumsq (deterministic)
#pragma unroll
    for (int o = 32; o >= 1; o >>= 1) yss += __shfl_xor(yss, o, 64);
    if (l == 0) red[w] = yss;
    __syncthreads();
    const float tot = red[0]+red[1]+red[2]+red[3];
    const float rni = 1.0f / fmaxf(sqrtf(tot), 1e-12f);

    float4* out4 = (float4*)(out + (size_t)r*ROWLEN);
#pragma unroll
    for (int it = 0; it < 4; ++it) {
        const int k = it*16 + w*4 + g;
        float4 v0 = make_float4(y[it][0]*rni, y[it][1]*rni, y[it][2]*rni, y[it][3]*rni);
        float4 v1 = make_float4(y[it][4]*rni, y[it][5]*rni, y[it][6]*rni, y[it][7]*rni);
        out4[k*32 + li*2]     = v0;
        out4[k*32 + li*2 + 1] = v1;
    }
}

extern "C" void kernel_launch(void* const* d_in, const int* in_sizes, int n_in,
                              void* d_out, int out_size, void* d_ws, size_t ws_size,
                              hipStream_t stream)
{
    const float* x     = (const float*)d_in[0];
    // d_in[1] = conv_w, d_in[2] = conv_b : provably unused (softmax cancels in intra-norm)
    const float* cent  = (const float*)d_in[3];
    const float* gamma = (const float*)d_in[4];
    const float* beta  = (const float*)d_in[5];
    float* out = (float*)d_out;

    float* partial = (float*)d_ws;          // 2*ROWS floats
    float* stats   = partial + 2*ROWS;      // 2*CB floats

    hipLaunchKernelGGL(k_stats,  dim3(ROWS), dim3(256), 0, stream, x, cent, partial);
    hipLaunchKernelGGL(k_reduce, dim3(CB),   dim3(256), 0, stream, partial, stats);
    hipLaunchKernelGGL(k_out,    dim3(ROWS), dim3(256), 0, stream, x, cent, stats, gamma, beta, out);
}

// Round 4
// 74.301 us; speedup vs baseline: 1.0911x; 1.0911x over previous
//
#include <hip/hip_runtime.h>

#define NB 4
#define CB 8
#define DB 196
#define MBd 128
#define KBc 64
#define ROWS (NB*CB*DB)        // 6272
#define ROWLEN (KBc*MBd)       // 8192
#define RPB 7                  // rows per block; 196 % 7 == 0 -> one channel per block
#define GRID1 (ROWS/RPB)       // 896
#define CSTR 132               // padded LDS row stride (floats), 528B, 16B aligned, conflict-free
#define CNTF ((float)(NB*DB*KBc*MBd))  // 6422528 per channel

typedef float floatx4 __attribute__((ext_vector_type(4)));

// ---------------- Kernel 1: per-block (single-channel) BN partial sums ----------------
__global__ __launch_bounds__(256) void k_stats(const float* __restrict__ x,
                                               const float* __restrict__ cent,
                                               float* __restrict__ partial)
{
    __shared__ float cs[KBc*CSTR];    // 33.8 KB padded centroids
    __shared__ float xs[RPB*MBd];     // 3.5 KB: 7 rows of x
    __shared__ float red[8];
    const int t  = threadIdx.x;
    const int rb = blockIdx.x * RPB;

    // stage centroids (8192 f32) -> padded LDS
    const floatx4* c4 = (const floatx4*)cent;
#pragma unroll
    for (int i = 0; i < 8; ++i) {
        int idx = i*256 + t;          // float4 index 0..2047
        int k   = idx >> 5;           // 32 float4 per centroid row
        int m4  = idx & 31;
        ((floatx4*)&cs[k*CSTR])[m4] = c4[idx];
    }
    // stage 7 rows of x (896 floats = 224 float4)
    if (t < RPB*MBd/4) ((floatx4*)xs)[t] = ((const floatx4*)(x + (size_t)rb*MBd))[t];
    __syncthreads();

    const int l  = t & 63;
    const int w  = t >> 6;
    const int g  = l >> 4;
    const int li = l & 15;

    float s1 = 0.f, s2 = 0.f;
    for (int ri = 0; ri < RPB; ++ri) {
        const float* xr_ = &xs[ri*MBd];
        // row L2 norm (redundant per wave, deterministic)
        float s = xr_[l]*xr_[l] + xr_[l+64]*xr_[l+64];
#pragma unroll
        for (int o = 32; o >= 1; o >>= 1) s += __shfl_xor(s, o, 64);
        const float xrn = 1.0f / fmaxf(sqrtf(s), 1e-12f);

        float xm[8];
#pragma unroll
        for (int j = 0; j < 4; ++j) xm[j]   = xr_[li*4+j]   * xrn;
#pragma unroll
        for (int j = 0; j < 4; ++j) xm[4+j] = xr_[64+li*4+j]* xrn;

#pragma unroll
        for (int it = 0; it < 4; ++it) {
            const int k = it*16 + w*4 + g;
            const float* cr = &cs[k*CSTR];
            float u[8]; float ss = 0.f;
#pragma unroll
            for (int j = 0; j < 4; ++j) { u[j]   = xm[j]   - cr[li*4+j];    ss = fmaf(u[j],  u[j],  ss); }
#pragma unroll
            for (int j = 0; j < 4; ++j) { u[4+j] = xm[4+j] - cr[64+li*4+j]; ss = fmaf(u[4+j],u[4+j],ss); }
#pragma unroll
            for (int o = 8; o >= 1; o >>= 1) ss += __shfl_xor(ss, o, 64);
            const float rn = 1.0f / fmaxf(sqrtf(ss), 1e-12f);
#pragma unroll
            for (int j = 0; j < 8; ++j) { float v = u[j]*rn; s1 += v; s2 = fmaf(v, v, s2); }
        }
    }
    // one block reduce for all 7 rows (same channel) — fixed order, deterministic
#pragma unroll
    for (int o = 32; o >= 1; o >>= 1) { s1 += __shfl_xor(s1, o, 64); s2 += __shfl_xor(s2, o, 64); }
    if (l == 0) { red[w] = s1; red[4+w] = s2; }
    __syncthreads();
    if (t == 0) {
        partial[2*blockIdx.x]   = red[0]+red[1]+red[2]+red[3];
        partial[2*blockIdx.x+1] = red[4]+red[5]+red[6]+red[7];
    }
}

// ---------------- Kernel 2: per-channel mean / inv_std ----------------
// block b of k_stats covers rows [b*7, b*7+7), all with channel c = (b/28) % 8.
// For channel c: contributing blocks are b = n*224 + c*28 + d7, n<4, d7<28 (112 blocks).
__global__ __launch_bounds__(128) void k_reduce(const float* __restrict__ partial,
                                                float* __restrict__ stats)
{
    __shared__ float rs1[128], rs2[128];
    const int c = blockIdx.x, t = threadIdx.x;
    float s1 = 0.f, s2 = 0.f;
    if (t < 112) {
        int n = t / 28, d7 = t % 28;
        int b = n*224 + c*28 + d7;
        s1 = partial[2*b]; s2 = partial[2*b+1];
    }
    rs1[t] = s1; rs2[t] = s2; __syncthreads();
#pragma unroll
    for (int sdiv = 64; sdiv >= 1; sdiv >>= 1) {
        if (t < sdiv) { rs1[t] += rs1[t+sdiv]; rs2[t] += rs2[t+sdiv]; }
        __syncthreads();
    }
    if (t == 0) {
        float mean = rs1[0] / CNTF;
        float var  = rs2[0] / CNTF - mean*mean;
        stats[2*c]   = mean;
        stats[2*c+1] = 1.0f / sqrtf(var + 1e-5f);
    }
}

// ---------------- Kernel 3: recompute, BN affine, final l2norm, NT write ----------------
__global__ __launch_bounds__(256) void k_out(const float* __restrict__ x,
                                             const float* __restrict__ cent,
                                             const float* __restrict__ stats,
                                             const float* __restrict__ gamma,
                                             const float* __restrict__ beta,
                                             float* __restrict__ out)
{
    __shared__ float cs[KBc*CSTR];
    __shared__ float xs[RPB*MBd];
    __shared__ float red[4];
    const int t  = threadIdx.x;
    const int rb = blockIdx.x * RPB;

    const floatx4* c4 = (const floatx4*)cent;
#pragma unroll
    for (int i = 0; i < 8; ++i) {
        int idx = i*256 + t;
        int k   = idx >> 5;
        int m4  = idx & 31;
        ((floatx4*)&cs[k*CSTR])[m4] = c4[idx];
    }
    if (t < RPB*MBd/4) ((floatx4*)xs)[t] = ((const floatx4*)(x + (size_t)rb*MBd))[t];
    __syncthreads();

    const int l  = t & 63;
    const int w  = t >> 6;
    const int g  = l >> 4;
    const int li = l & 15;

    const int c = (blockIdx.x / 28) % CB;   // all 7 rows share this channel
    const float mean = stats[2*c];
    const float istd = stats[2*c+1];
    const float aa = istd * gamma[c];
    const float bb = beta[c] - mean * aa;

    for (int ri = 0; ri < RPB; ++ri) {
        const float* xr_ = &xs[ri*MBd];
        float s = xr_[l]*xr_[l] + xr_[l+64]*xr_[l+64];
#pragma unroll
        for (int o = 32; o >= 1; o >>= 1) s += __shfl_xor(s, o, 64);
        const float xrn = 1.0f / fmaxf(sqrtf(s), 1e-12f);

        float xm[8];
#pragma unroll
        for (int j = 0; j < 4; ++j) xm[j]   = xr_[li*4+j]   * xrn;
#pragma unroll
        for (int j = 0; j < 4; ++j) xm[4+j] = xr_[64+li*4+j]* xrn;

        float y[4][8];
        float yss = 0.f;
#pragma unroll
        for (int it = 0; it < 4; ++it) {
            const int k = it*16 + w*4 + g;
            const float* cr = &cs[k*CSTR];
            float u[8]; float ss = 0.f;
#pragma unroll
            for (int j = 0; j < 4; ++j) { u[j]   = xm[j]   - cr[li*4+j];    ss = fmaf(u[j],  u[j],  ss); }
#pragma unroll
            for (int j = 0; j < 4; ++j) { u[4+j] = xm[4+j] - cr[64+li*4+j]; ss = fmaf(u[4+j],u[4+j],ss); }
#pragma unroll
            for (int o = 8; o >= 1; o >>= 1) ss += __shfl_xor(ss, o, 64);
            const float rn = 1.0f / fmaxf(sqrtf(ss), 1e-12f);
#pragma unroll
            for (int j = 0; j < 8; ++j) {
                float v  = u[j]*rn;
                float yy = fmaf(v, aa, bb);
                y[it][j] = yy;
                yss = fmaf(yy, yy, yss);
            }
        }
        // row sumsq across block (4 waves), deterministic
#pragma unroll
        for (int o = 32; o >= 1; o >>= 1) yss += __shfl_xor(yss, o, 64);
        __syncthreads();               // protect red[] from previous row
        if (l == 0) red[w] = yss;
        __syncthreads();
        const float tot = red[0]+red[1]+red[2]+red[3];
        const float rni = 1.0f / fmaxf(sqrtf(tot), 1e-12f);

        floatx4* out4 = (floatx4*)(out + (size_t)(rb+ri)*ROWLEN);
#pragma unroll
        for (int it = 0; it < 4; ++it) {
            const int k = it*16 + w*4 + g;
            floatx4 v0 = { y[it][0]*rni, y[it][1]*rni, y[it][2]*rni, y[it][3]*rni };
            floatx4 v1 = { y[it][4]*rni, y[it][5]*rni, y[it][6]*rni, y[it][7]*rni };
            __builtin_nontemporal_store(v0, &out4[k*32 + li]);        // m = li*4 .. +3
            __builtin_nontemporal_store(v1, &out4[k*32 + 16 + li]);   // m = 64+li*4 .. +3
        }
    }
}

extern "C" void kernel_launch(void* const* d_in, const int* in_sizes, int n_in,
                              void* d_out, int out_size, void* d_ws, size_t ws_size,
                              hipStream_t stream)
{
    const float* x     = (const float*)d_in[0];
    // d_in[1] = conv_w, d_in[2] = conv_b : provably unused (softmax cancels in intra-norm)
    const float* cent  = (const float*)d_in[3];
    const float* gamma = (const float*)d_in[4];
    const float* beta  = (const float*)d_in[5];
    float* out = (float*)d_out;

    float* partial = (float*)d_ws;            // 2*GRID1 floats
    float* stats   = partial + 2*GRID1;       // 2*CB floats

    hipLaunchKernelGGL(k_stats,  dim3(GRID1), dim3(256), 0, stream, x, cent, partial);
    hipLaunchKernelGGL(k_reduce, dim3(CB),    dim3(128), 0, stream, partial, stats);
    hipLaunchKernelGGL(k_out,    dim3(GRID1), dim3(256), 0, stream, x, cent, stats, gamma, beta, out);
}

// Round 5
// 65.278 us; speedup vs baseline: 1.2419x; 1.1382x over previous
//
#include <hip/hip_runtime.h>

#define NB 4
#define CB 8
#define DB 196
#define MBd 128
#define KBc 64
#define ROWS (NB*CB*DB)        // 6272
#define ROWLEN (KBc*MBd)       // 8192
#define RPB 7                  // rows per block (one channel per block); 196 % 7 == 0
#define GRID (ROWS/RPB)        // 896
#define CNTF 6422528.0f        // elements per channel

typedef float floatx4 __attribute__((ext_vector_type(4)));

__device__ __forceinline__ float dot4(floatx4 a, floatx4 b){
    return fmaf(a.x,b.x, fmaf(a.y,b.y, fmaf(a.z,b.z, a.w*b.w)));
}

// ---------------- Kernel 1: per-block S1 partial + per-row SV via dot trick ----------------
// sv contribution per (row,k): (Sx - Sc_k) * rsqrt(1 - 2*xn.c_k + |c_k|^2); Sum v^2 is exact const.
__global__ __launch_bounds__(256) void k_stats(const float* __restrict__ x,
                                               const float* __restrict__ cent,
                                               float* __restrict__ sv_ws,
                                               float* __restrict__ partial,
                                               float* __restrict__ opc_ws)
{
    __shared__ float cs[KBc*MBd];     // 32 KB centroids
    __shared__ float sopc[KBc];       // 1 + |c_k|^2
    __shared__ float ssc[KBc];        // sum_m c_km
    __shared__ float sp1[256], sp2[256];
    __shared__ float svp[RPB*4];
    __shared__ float sv7[RPB];

    const int t  = threadIdx.x;
    const int rb = blockIdx.x * RPB;
    const floatx4* c4 = (const floatx4*)cent;
    floatx4* cs4 = (floatx4*)cs;
#pragma unroll
    for (int i = 0; i < 8; ++i) cs4[i*256 + t] = c4[i*256 + t];
    __syncthreads();

    // per-k row sums (4 threads per k)
    {
        const int kk = t >> 2, q = t & 3;
        const floatx4* crow = &cs4[kk*32 + q*8];
        float ps = 0.f, pc = 0.f;
#pragma unroll
        for (int f = 0; f < 8; ++f) { floatx4 v = crow[f]; ps += (v.x+v.y)+(v.z+v.w); pc += dot4(v,v); }
        sp1[t] = ps; sp2[t] = pc;
    }
    __syncthreads();
    if (t < KBc) {
        ssc[t]  = (sp1[4*t]+sp1[4*t+1])+(sp1[4*t+2]+sp1[4*t+3]);
        sopc[t] = 1.0f + ((sp2[4*t]+sp2[4*t+1])+(sp2[4*t+2]+sp2[4*t+3]));
    }
    __syncthreads();
    if (blockIdx.x == 0 && t < KBc) opc_ws[t] = sopc[t];

    const int l = t & 63, w = t >> 6, g = (l >> 4), li = l & 15;
    const floatx4* xg = (const floatx4*)x;

    for (int ri = 0; ri < RPB; ++ri) {
        const int row = rb + ri;
        floatx4 xa = xg[row*32 + li];
        floatx4 xb = xg[row*32 + 16 + li];
        float s2 = dot4(xa,xa) + dot4(xb,xb);
        float sx = ((xa.x+xa.y)+(xa.z+xa.w)) + ((xb.x+xb.y)+(xb.z+xb.w));
#pragma unroll
        for (int o = 8; o >= 1; o >>= 1) { s2 += __shfl_xor(s2,o,64); sx += __shfl_xor(sx,o,64); }
        const float xrn = __builtin_amdgcn_rsqf(s2);   // |x| >= ~8, clamp inert
        const float Sx  = sx * xrn;
        float sva = 0.f;
#pragma unroll
        for (int it = 0; it < 4; ++it) {
            const int k = it*16 + w*4 + g;
            float d = dot4(xa, cs4[k*32+li]) + dot4(xb, cs4[k*32+16+li]);
#pragma unroll
            for (int o = 8; o >= 1; o >>= 1) d += __shfl_xor(d,o,64);
            const float dn = xrn * d;
            const float rn = __builtin_amdgcn_rsqf(fmaf(-2.f, dn, sopc[k]));  // dist^2 >= ~20
            sva = fmaf(Sx - ssc[k], rn, sva);
        }
        // wave sum: each sv appears 16x (identical across group lanes) -> exact /16
#pragma unroll
        for (int o = 32; o >= 1; o >>= 1) sva += __shfl_xor(sva,o,64);
        if (l == 0) svp[ri*4 + w] = sva * 0.0625f;
    }
    __syncthreads();
    if (t < RPB) {
        float s = (svp[4*t]+svp[4*t+1])+(svp[4*t+2]+svp[4*t+3]);
        sv_ws[rb + t] = s;
        sv7[t] = s;
    }
    __syncthreads();
    if (t == 0) {
        float s = 0.f;
#pragma unroll
        for (int i = 0; i < RPB; ++i) s += sv7[i];
        partial[blockIdx.x] = s;
    }
}

// ---------------- Kernel 2 (fused stats) + output: barrier-free row loop, NT stores ----------------
__global__ __launch_bounds__(256) void k_out(const float* __restrict__ x,
                                             const float* __restrict__ cent,
                                             const float* __restrict__ sv_ws,
                                             const float* __restrict__ partial,
                                             const float* __restrict__ opc_ws,
                                             const float* __restrict__ gamma,
                                             const float* __restrict__ beta,
                                             float* __restrict__ out)
{
    __shared__ float cs[KBc*MBd];
    __shared__ float sopc[KBc];
    __shared__ float sab[2];
    const int t  = threadIdx.x;
    const int rb = blockIdx.x * RPB;
    const int c  = (blockIdx.x / 28) % CB;
    const floatx4* c4 = (const floatx4*)cent;
    floatx4* cs4 = (floatx4*)cs;
#pragma unroll
    for (int i = 0; i < 8; ++i) cs4[i*256 + t] = c4[i*256 + t];
    if (t >= 64 && t < 128) sopc[t-64] = opc_ws[t-64];
    if (t < 64) {
        // wave 0: reduce this channel's 112 partials (fixed tree, deterministic)
        float s1 = 0.f;
        if (t < 56) {
            const int j0 = t, j1 = t + 56;
            const int b0 = (j0/28)*224 + c*28 + (j0%28);
            const int b1 = (j1/28)*224 + c*28 + (j1%28);
            s1 = partial[b0] + partial[b1];
        }
#pragma unroll
        for (int o = 32; o >= 1; o >>= 1) s1 += __shfl_xor(s1,o,64);
        if (t == 0) {
            const float mean = s1 / CNTF;
            const float var  = 0.0078125f - mean*mean;     // E[v^2] = 50176/6422528 exactly
            const float istd = __builtin_amdgcn_rsqf(var + 1e-5f);
            const float aa = istd * gamma[c];
            const float bb = beta[c] - mean * aa;
            sab[0] = aa; sab[1] = bb;
        }
    }
    __syncthreads();
    const float aa = sab[0], bb = sab[1];

    const int l = t & 63, w = t >> 6, g = (l >> 4), li = l & 15;
    const floatx4* xg = (const floatx4*)x;

    for (int ri = 0; ri < RPB; ++ri) {
        const int row = rb + ri;
        floatx4 xa = xg[row*32 + li];
        floatx4 xb = xg[row*32 + 16 + li];
        float s2 = dot4(xa,xa) + dot4(xb,xb);
#pragma unroll
        for (int o = 8; o >= 1; o >>= 1) s2 += __shfl_xor(s2,o,64);
        const float xrn = __builtin_amdgcn_rsqf(s2);
        const floatx4 va = xa * xrn, vb = xb * xrn;
        // closed-form row sumsq: 64*aa^2 + 2*aa*bb*SV + 8192*bb^2  (Sum v^2 over row = 64 exact)
        const float SVr = sv_ws[row];
        const float q   = fmaf(64.f*aa, aa, fmaf(2.f*aa*bb, SVr, 8192.f*bb*bb));
        const float rni = __builtin_amdgcn_rsqf(q);
        const float f1  = aa * rni;
        const float c2  = bb * rni;
        floatx4* outr = (floatx4*)out + (size_t)row*2048;
#pragma unroll
        for (int it = 0; it < 4; ++it) {
            const int k = it*16 + w*4 + g;
            const floatx4 ca = cs4[k*32+li];
            const floatx4 cb = cs4[k*32+16+li];
            float d = dot4(va,ca) + dot4(vb,cb);
#pragma unroll
            for (int o = 8; o >= 1; o >>= 1) d += __shfl_xor(d,o,64);
            const float rn = __builtin_amdgcn_rsqf(fmaf(-2.f, d, sopc[k]));
            const float cc = f1 * rn;
            floatx4 o1, o2;
            o1.x = fmaf(va.x - ca.x, cc, c2); o1.y = fmaf(va.y - ca.y, cc, c2);
            o1.z = fmaf(va.z - ca.z, cc, c2); o1.w = fmaf(va.w - ca.w, cc, c2);
            o2.x = fmaf(vb.x - cb.x, cc, c2); o2.y = fmaf(vb.y - cb.y, cc, c2);
            o2.z = fmaf(vb.z - cb.z, cc, c2); o2.w = fmaf(vb.w - cb.w, cc, c2);
            __builtin_nontemporal_store(o1, &outr[k*32 + li]);
            __builtin_nontemporal_store(o2, &outr[k*32 + 16 + li]);
        }
    }
}

extern "C" void kernel_launch(void* const* d_in, const int* in_sizes, int n_in,
                              void* d_out, int out_size, void* d_ws, size_t ws_size,
                              hipStream_t stream)
{
    const float* x     = (const float*)d_in[0];
    // d_in[1]=conv_w, d_in[2]=conv_b : provably unused (softmax cancels in intra-norm)
    const float* cent  = (const float*)d_in[3];
    const float* gamma = (const float*)d_in[4];
    const float* beta  = (const float*)d_in[5];
    float* out = (float*)d_out;

    float* sv_ws   = (float*)d_ws;             // 6272 floats: per-row Sum v
    float* partial = sv_ws + ROWS;             // 896 floats: per-block S1
    float* opc_ws  = partial + GRID;           // 64 floats: 1 + |c_k|^2

    hipLaunchKernelGGL(k_stats, dim3(GRID), dim3(256), 0, stream, x, cent, sv_ws, partial, opc_ws);
    hipLaunchKernelGGL(k_out,   dim3(GRID), dim3(256), 0, stream, x, cent, sv_ws, partial, opc_ws,
                       gamma, beta, out);
}

// Round 6
// 62.854 us; speedup vs baseline: 1.2898x; 1.0386x over previous
//
#include <hip/hip_runtime.h>

#define NB 4
#define CB 8
#define DB 196
#define MBd 128
#define KBc 64
#define ROWS (NB*CB*DB)        // 6272
#define RPB 7                  // rows per block (one channel per block); 196 % 7 == 0
#define GRID (ROWS/RPB)        // 896
#define CNTF 6422528.0f        // elements per channel

typedef float floatx4 __attribute__((ext_vector_type(4)));

__device__ __forceinline__ float dot4(floatx4 a, floatx4 b){
    return fmaf(a.x,b.x, fmaf(a.y,b.y, fmaf(a.z,b.z, a.w*b.w)));
}

// ================= FAST PATH (needs ~1.66 MB ws) =================
// K1: per-(row,k) rn, per-row xrn & SV, per-block S1 — all cross-lane work lives here.
__global__ __launch_bounds__(256) void k_stats(const float* __restrict__ x,
                                               const float* __restrict__ cent,
                                               float* __restrict__ rn_ws,
                                               float* __restrict__ xrn_ws,
                                               float* __restrict__ sv_ws,
                                               float* __restrict__ partial)
{
    __shared__ float cs[KBc*MBd];     // 32 KB centroids
    __shared__ float sopc[KBc];       // 1 + |c_k|^2
    __shared__ float ssc[KBc];        // sum_m c_km
    __shared__ float sp1[256], sp2[256];
    __shared__ float svp[RPB*4];
    __shared__ float sv7[RPB];

    const int t  = threadIdx.x;
    const int rb = blockIdx.x * RPB;
    const floatx4* c4 = (const floatx4*)cent;
    floatx4* cs4 = (floatx4*)cs;
#pragma unroll
    for (int i = 0; i < 8; ++i) cs4[i*256 + t] = c4[i*256 + t];
    __syncthreads();

    {   // per-k row sums (4 threads per k)
        const int kk = t >> 2, q = t & 3;
        const floatx4* crow = &cs4[kk*32 + q*8];
        float ps = 0.f, pc = 0.f;
#pragma unroll
        for (int f = 0; f < 8; ++f) { floatx4 v = crow[f]; ps += (v.x+v.y)+(v.z+v.w); pc += dot4(v,v); }
        sp1[t] = ps; sp2[t] = pc;
    }
    __syncthreads();
    if (t < KBc) {
        ssc[t]  = (sp1[4*t]+sp1[4*t+1])+(sp1[4*t+2]+sp1[4*t+3]);
        sopc[t] = 1.0f + ((sp2[4*t]+sp2[4*t+1])+(sp2[4*t+2]+sp2[4*t+3]));
    }
    __syncthreads();

    const int l = t & 63, w = t >> 6, g = (l >> 4), li = l & 15;
    const floatx4* xg = (const floatx4*)x;

    for (int ri = 0; ri < RPB; ++ri) {
        const int row = rb + ri;
        floatx4 xa = xg[row*32 + li];
        floatx4 xb = xg[row*32 + 16 + li];
        float s2 = dot4(xa,xa) + dot4(xb,xb);
        float sx = ((xa.x+xa.y)+(xa.z+xa.w)) + ((xb.x+xb.y)+(xb.z+xb.w));
#pragma unroll
        for (int o = 8; o >= 1; o >>= 1) { s2 += __shfl_xor(s2,o,64); sx += __shfl_xor(sx,o,64); }
        const float xrn = __builtin_amdgcn_rsqf(s2);   // |x|^2 >= ~70, clamp inert
        const float Sx  = sx * xrn;
        float sva = 0.f;
        floatx4 rn4;
#pragma unroll
        for (int it = 0; it < 4; ++it) {
            const int k = it*16 + w*4 + g;
            float d = dot4(xa, cs4[k*32+li]) + dot4(xb, cs4[k*32+16+li]);
#pragma unroll
            for (int o = 8; o >= 1; o >>= 1) d += __shfl_xor(d,o,64);
            const float dn = xrn * d;
            const float rn = __builtin_amdgcn_rsqf(fmaf(-2.f, dn, sopc[k]));  // dist^2 >= ~20
            rn4[it] = rn;
            sva = fmaf(Sx - ssc[k], rn, sva);
        }
        // each k's sv replicated 16x across its group -> exact /16 after full-wave sum
#pragma unroll
        for (int o = 32; o >= 1; o >>= 1) sva += __shfl_xor(sva,o,64);
        if (li == 0) *(floatx4*)&rn_ws[(size_t)row*KBc + (w*4+g)*4] = rn4;
        if (t == 0) xrn_ws[row] = xrn;
        if (l == 0) svp[ri*4 + w] = sva * 0.0625f;
    }
    __syncthreads();
    if (t < RPB) {
        float s = (svp[4*t]+svp[4*t+1])+(svp[4*t+2]+svp[4*t+3]);
        sv_ws[rb + t] = s;
        sv7[t] = s;
    }
    __syncthreads();
    if (t == 0) {
        float s = 0.f;
#pragma unroll
        for (int i = 0; i < RPB; ++i) s += sv7[i];
        partial[blockIdx.x] = s;
    }
}

// K2: pure stream kernel — no LDS staging, no shuffles, no barriers in row loop.
__global__ __launch_bounds__(256) void k_out(const float* __restrict__ x,
                                             const float* __restrict__ cent,
                                             const float* __restrict__ rn_ws,
                                             const float* __restrict__ xrn_ws,
                                             const float* __restrict__ sv_ws,
                                             const float* __restrict__ partial,
                                             const float* __restrict__ gamma,
                                             const float* __restrict__ beta,
                                             float* __restrict__ out)
{
    __shared__ float sab[2];
    const int t  = threadIdx.x;
    const int rb = blockIdx.x * RPB;
    const int c  = (blockIdx.x / 28) % CB;
    const int l = t & 63, w = t >> 6, g = (l >> 4), li = l & 15;
    const floatx4* c4 = (const floatx4*)cent;

    // loop-invariant centroid fragments -> registers (L2-resident, broadcast)
    floatx4 ca[4], cb[4];
#pragma unroll
    for (int it = 0; it < 4; ++it) {
        const int k = it*16 + w*4 + g;
        ca[it] = c4[k*32 + li];
        cb[it] = c4[k*32 + 16 + li];
    }

    if (t < 64) {   // wave 0: reduce this channel's 112 partials (fixed tree)
        float s1 = 0.f;
        if (t < 56) {
            const int j0 = t, j1 = t + 56;
            const int b0 = (j0/28)*224 + c*28 + (j0%28);
            const int b1 = (j1/28)*224 + c*28 + (j1%28);
            s1 = partial[b0] + partial[b1];
        }
#pragma unroll
        for (int o = 32; o >= 1; o >>= 1) s1 += __shfl_xor(s1,o,64);
        if (t == 0) {
            const float mean = s1 / CNTF;
            const float var  = 0.0078125f - mean*mean;   // E[v^2] = 50176/6422528 exact
            const float istd = __builtin_amdgcn_rsqf(var + 1e-5f);
            const float aa = istd * gamma[c];
            const float bb = beta[c] - mean * aa;
            sab[0] = aa; sab[1] = bb;
        }
    }
    __syncthreads();
    const float aa = sab[0], bb = sab[1];
    const float qa = fmaf(64.f*aa, aa, 8192.f*bb*bb);
    const float qb = 2.f*aa*bb;

    const floatx4* xg = (const floatx4*)x;
    for (int ri = 0; ri < RPB; ++ri) {
        const int row = rb + ri;
        floatx4 xa = xg[row*32 + li];
        floatx4 xb = xg[row*32 + 16 + li];
        const float xrn = xrn_ws[row];
        const float SVr = sv_ws[row];
        floatx4 rn4 = *(const floatx4*)&rn_ws[(size_t)row*KBc + (w*4+g)*4];
        const float rni = __builtin_amdgcn_rsqf(fmaf(qb, SVr, qa));  // closed-form row norm
        const float f1  = aa * rni;
        const float c2  = bb * rni;
        const floatx4 va = xa * xrn, vb = xb * xrn;
        floatx4* outr = (floatx4*)out + (size_t)row*2048;
#pragma unroll
        for (int it = 0; it < 4; ++it) {
            const int k = it*16 + w*4 + g;
            const float cc = f1 * rn4[it];
            floatx4 o1, o2;
            o1.x = fmaf(va.x - ca[it].x, cc, c2); o1.y = fmaf(va.y - ca[it].y, cc, c2);
            o1.z = fmaf(va.z - ca[it].z, cc, c2); o1.w = fmaf(va.w - ca[it].w, cc, c2);
            o2.x = fmaf(vb.x - cb[it].x, cc, c2); o2.y = fmaf(vb.y - cb[it].y, cc, c2);
            o2.z = fmaf(vb.z - cb[it].z, cc, c2); o2.w = fmaf(vb.w - cb[it].w, cc, c2);
            __builtin_nontemporal_store(o1, &outr[k*32 + li]);
            __builtin_nontemporal_store(o2, &outr[k*32 + 16 + li]);
        }
    }
}

// ================= FALLBACK PATH (round-5 proven, ~29 KB ws) =================
__global__ __launch_bounds__(256) void k_stats_f(const float* __restrict__ x,
                                                 const float* __restrict__ cent,
                                                 float* __restrict__ sv_ws,
                                                 float* __restrict__ partial,
                                                 float* __restrict__ opc_ws)
{
    __shared__ float cs[KBc*MBd];
    __shared__ float sopc[KBc];
    __shared__ float ssc[KBc];
    __shared__ float sp1[256], sp2[256];
    __shared__ float svp[RPB*4];
    __shared__ float sv7[RPB];

    const int t  = threadIdx.x;
    const int rb = blockIdx.x * RPB;
    const floatx4* c4 = (const floatx4*)cent;
    floatx4* cs4 = (floatx4*)cs;
#pragma unroll
    for (int i = 0; i < 8; ++i) cs4[i*256 + t] = c4[i*256 + t];
    __syncthreads();
    {
        const int kk = t >> 2, q = t & 3;
        const floatx4* crow = &cs4[kk*32 + q*8];
        float ps = 0.f, pc = 0.f;
#pragma unroll
        for (int f = 0; f < 8; ++f) { floatx4 v = crow[f]; ps += (v.x+v.y)+(v.z+v.w); pc += dot4(v,v); }
        sp1[t] = ps; sp2[t] = pc;
    }
    __syncthreads();
    if (t < KBc) {
        ssc[t]  = (sp1[4*t]+sp1[4*t+1])+(sp1[4*t+2]+sp1[4*t+3]);
        sopc[t] = 1.0f + ((sp2[4*t]+sp2[4*t+1])+(sp2[4*t+2]+sp2[4*t+3]));
    }
    __syncthreads();
    if (blockIdx.x == 0 && t < KBc) opc_ws[t] = sopc[t];

    const int l = t & 63, w = t >> 6, g = (l >> 4), li = l & 15;
    const floatx4* xg = (const floatx4*)x;
    for (int ri = 0; ri < RPB; ++ri) {
        const int row = rb + ri;
        floatx4 xa = xg[row*32 + li];
        floatx4 xb = xg[row*32 + 16 + li];
        float s2 = dot4(xa,xa) + dot4(xb,xb);
        float sx = ((xa.x+xa.y)+(xa.z+xa.w)) + ((xb.x+xb.y)+(xb.z+xb.w));
#pragma unroll
        for (int o = 8; o >= 1; o >>= 1) { s2 += __shfl_xor(s2,o,64); sx += __shfl_xor(sx,o,64); }
        const float xrn = __builtin_amdgcn_rsqf(s2);
        const float Sx  = sx * xrn;
        float sva = 0.f;
#pragma unroll
        for (int it = 0; it < 4; ++it) {
            const int k = it*16 + w*4 + g;
            float d = dot4(xa, cs4[k*32+li]) + dot4(xb, cs4[k*32+16+li]);
#pragma unroll
            for (int o = 8; o >= 1; o >>= 1) d += __shfl_xor(d,o,64);
            const float dn = xrn * d;
            const float rn = __builtin_amdgcn_rsqf(fmaf(-2.f, dn, sopc[k]));
            sva = fmaf(Sx - ssc[k], rn, sva);
        }
#pragma unroll
        for (int o = 32; o >= 1; o >>= 1) sva += __shfl_xor(sva,o,64);
        if (l == 0) svp[ri*4 + w] = sva * 0.0625f;
    }
    __syncthreads();
    if (t < RPB) {
        float s = (svp[4*t]+svp[4*t+1])+(svp[4*t+2]+svp[4*t+3]);
        sv_ws[rb + t] = s;
        sv7[t] = s;
    }
    __syncthreads();
    if (t == 0) {
        float s = 0.f;
#pragma unroll
        for (int i = 0; i < RPB; ++i) s += sv7[i];
        partial[blockIdx.x] = s;
    }
}

__global__ __launch_bounds__(256) void k_out_f(const float* __restrict__ x,
                                               const float* __restrict__ cent,
                                               const float* __restrict__ sv_ws,
                                               const float* __restrict__ partial,
                                               const float* __restrict__ opc_ws,
                                               const float* __restrict__ gamma,
                                               const float* __restrict__ beta,
                                               float* __restrict__ out)
{
    __shared__ float cs[KBc*MBd];
    __shared__ float sopc[KBc];
    __shared__ float sab[2];
    const int t  = threadIdx.x;
    const int rb = blockIdx.x * RPB;
    const int c  = (blockIdx.x / 28) % CB;
    const floatx4* c4 = (const floatx4*)cent;
    floatx4* cs4 = (floatx4*)cs;
#pragma unroll
    for (int i = 0; i < 8; ++i) cs4[i*256 + t] = c4[i*256 + t];
    if (t >= 64 && t < 128) sopc[t-64] = opc_ws[t-64];
    if (t < 64) {
        float s1 = 0.f;
        if (t < 56) {
            const int j0 = t, j1 = t + 56;
            const int b0 = (j0/28)*224 + c*28 + (j0%28);
            const int b1 = (j1/28)*224 + c*28 + (j1%28);
            s1 = partial[b0] + partial[b1];
        }
#pragma unroll
        for (int o = 32; o >= 1; o >>= 1) s1 += __shfl_xor(s1,o,64);
        if (t == 0) {
            const float mean = s1 / CNTF;
            const float var  = 0.0078125f - mean*mean;
            const float istd = __builtin_amdgcn_rsqf(var + 1e-5f);
            const float aa = istd * gamma[c];
            const float bb = beta[c] - mean * aa;
            sab[0] = aa; sab[1] = bb;
        }
    }
    __syncthreads();
    const float aa = sab[0], bb = sab[1];

    const int l = t & 63, w = t >> 6, g = (l >> 4), li = l & 15;
    const floatx4* xg = (const floatx4*)x;
    for (int ri = 0; ri < RPB; ++ri) {
        const int row = rb + ri;
        floatx4 xa = xg[row*32 + li];
        floatx4 xb = xg[row*32 + 16 + li];
        float s2 = dot4(xa,xa) + dot4(xb,xb);
#pragma unroll
        for (int o = 8; o >= 1; o >>= 1) s2 += __shfl_xor(s2,o,64);
        const float xrn = __builtin_amdgcn_rsqf(s2);
        const floatx4 va = xa * xrn, vb = xb * xrn;
        const float SVr = sv_ws[row];
        const float q   = fmaf(64.f*aa, aa, fmaf(2.f*aa*bb, SVr, 8192.f*bb*bb));
        const float rni = __builtin_amdgcn_rsqf(q);
        const float f1  = aa * rni;
        const float c2  = bb * rni;
        floatx4* outr = (floatx4*)out + (size_t)row*2048;
#pragma unroll
        for (int it = 0; it < 4; ++it) {
            const int k = it*16 + w*4 + g;
            const floatx4 cca = cs4[k*32+li];
            const floatx4 ccb = cs4[k*32+16+li];
            float d = dot4(va,cca) + dot4(vb,ccb);
#pragma unroll
            for (int o = 8; o >= 1; o >>= 1) d += __shfl_xor(d,o,64);
            const float rn = __builtin_amdgcn_rsqf(fmaf(-2.f, d, sopc[k]));
            const float cc = f1 * rn;
            floatx4 o1, o2;
            o1.x = fmaf(va.x - cca.x, cc, c2); o1.y = fmaf(va.y - cca.y, cc, c2);
            o1.z = fmaf(va.z - cca.z, cc, c2); o1.w = fmaf(va.w - cca.w, cc, c2);
            o2.x = fmaf(vb.x - ccb.x, cc, c2); o2.y = fmaf(vb.y - ccb.y, cc, c2);
            o2.z = fmaf(vb.z - ccb.z, cc, c2); o2.w = fmaf(vb.w - ccb.w, cc, c2);
            __builtin_nontemporal_store(o1, &outr[k*32 + li]);
            __builtin_nontemporal_store(o2, &outr[k*32 + 16 + li]);
        }
    }
}

extern "C" void kernel_launch(void* const* d_in, const int* in_sizes, int n_in,
                              void* d_out, int out_size, void* d_ws, size_t ws_size,
                              hipStream_t stream)
{
    const float* x     = (const float*)d_in[0];
    // d_in[1]=conv_w, d_in[2]=conv_b : provably unused (softmax cancels in intra-norm)
    const float* cent  = (const float*)d_in[3];
    const float* gamma = (const float*)d_in[4];
    const float* beta  = (const float*)d_in[5];
    float* out = (float*)d_out;

    const size_t need = (size_t)(ROWS*KBc + ROWS + ROWS + GRID) * sizeof(float);
    if (ws_size >= need) {
        float* rn_ws   = (float*)d_ws;                 // 6272*64
        float* xrn_ws  = rn_ws + (size_t)ROWS*KBc;     // 6272
        float* sv_ws   = xrn_ws + ROWS;                // 6272
        float* partial = sv_ws + ROWS;                 // 896
        hipLaunchKernelGGL(k_stats, dim3(GRID), dim3(256), 0, stream,
                           x, cent, rn_ws, xrn_ws, sv_ws, partial);
        hipLaunchKernelGGL(k_out,   dim3(GRID), dim3(256), 0, stream,
                           x, cent, rn_ws, xrn_ws, sv_ws, partial, gamma, beta, out);
    } else {
        float* sv_ws   = (float*)d_ws;
        float* partial = sv_ws + ROWS;
        float* opc_ws  = partial + GRID;
        hipLaunchKernelGGL(k_stats_f, dim3(GRID), dim3(256), 0, stream,
                           x, cent, sv_ws, partial, opc_ws);
        hipLaunchKernelGGL(k_out_f,   dim3(GRID), dim3(256), 0, stream,
                           x, cent, sv_ws, partial, opc_ws, gamma, beta, out);
    }
}